// Round 8
// baseline (202.370 us; speedup 1.0000x reference)
//
#include <hip/hip_runtime.h>

typedef __bf16 bf16_t;
typedef __bf16 bf16x8 __attribute__((ext_vector_type(8)));
typedef __bf16 bf16x4 __attribute__((ext_vector_type(4)));
typedef short  s16x4  __attribute__((ext_vector_type(4)));
typedef float  f32x4  __attribute__((ext_vector_type(4)));
typedef unsigned int u32;

#define BB 2
#define SS 2048
#define EE 768
#define HH 12
#define DD 64
#define NROW (BB*SS)   // 4096

// async global->LDS, 16B per lane. LDS dest = firstlane(base)+lane*16 (linear).
#define GLDS16(gp, lp) __builtin_amdgcn_global_load_lds( \
    (const __attribute__((address_space(1))) u32*)(gp),   \
    (__attribute__((address_space(3))) u32*)(lp), 16, 0, 0)

#if __has_builtin(__builtin_amdgcn_mfma_f32_16x16x16bf16_1k)
#define MFMA16_BUILTIN 1
static __device__ __forceinline__ f32x4 mfma_16x16x16_bf16(bf16x4 a, bf16x4 b, f32x4 c) {
  return __builtin_amdgcn_mfma_f32_16x16x16bf16_1k(
      __builtin_bit_cast(s16x4, a), __builtin_bit_cast(s16x4, b), c, 0, 0, 0);
}
#else
#define MFMA16_BUILTIN 0
static __device__ __forceinline__ f32x4 mfma_16x16x16_bf16(bf16x4 a, bf16x4 b, f32x4 c) {
  asm volatile("v_mfma_f32_16x16x16_bf16 %0, %1, %2, %0" : "+v"(c) : "v"(a), "v"(b));
  return c;
}
#endif

// ---------------- pack weights: wt[z][n][k] = w_z[k][n] (bf16) ----------------
__global__ __launch_bounds__(256) void pack_w_kernel(
    const float* __restrict__ wq, const float* __restrict__ wk,
    const float* __restrict__ wv, const float* __restrict__ wo,
    bf16_t* __restrict__ wt)
{
  __shared__ float tile[64][65];
  const float* src = (blockIdx.z==0)?wq:(blockIdx.z==1)?wk:(blockIdx.z==2)?wv:wo;
  const int k0 = blockIdx.x*64, n0 = blockIdx.y*64;
  const int t = threadIdx.x;
  #pragma unroll
  for (int it=0; it<16; ++it) {
    int idx = it*256+t, r = idx>>6, c = idx&63;
    tile[r][c] = src[(size_t)(k0+r)*EE + n0 + c];
  }
  __syncthreads();
  bf16_t* dst = wt + (size_t)blockIdx.z*EE*EE;
  #pragma unroll
  for (int it=0; it<16; ++it) {
    int idx = it*256+t, r = idx>>6, c = idx&63;
    dst[(size_t)(n0+r)*EE + k0 + c] = (bf16_t)tile[c][r];
  }
}

// ---------------- LayerNorm (fp32 in, bf16 out) ----------------
__global__ __launch_bounds__(256) void ln_kernel(
    const float* __restrict__ x, const float* __restrict__ w,
    const float* __restrict__ bvec, bf16_t* __restrict__ xn)
{
  const int row = blockIdx.x, t = threadIdx.x;
  const float* xr = x + (size_t)row*EE;
  float v0 = xr[t], v1 = xr[t+256], v2 = xr[t+512];
  float s  = v0+v1+v2;
  float ss = v0*v0 + v1*v1 + v2*v2;
  #pragma unroll
  for (int m=1; m<64; m<<=1) { s += __shfl_xor(s,m); ss += __shfl_xor(ss,m); }
  __shared__ float red[2][4];
  const int wid = t>>6, lane = t&63;
  if (lane==0) { red[0][wid]=s; red[1][wid]=ss; }
  __syncthreads();
  s  = red[0][0]+red[0][1]+red[0][2]+red[0][3];
  ss = red[1][0]+red[1][1]+red[1][2]+red[1][3];
  const float mu   = s*(1.0f/EE);
  const float rstd = rsqrtf(ss*(1.0f/EE) - mu*mu + 1e-5f);
  bf16_t* xo = xn + (size_t)row*EE;
  xo[t      ] = (bf16_t)((v0-mu)*rstd*w[t      ] + bvec[t      ]);
  xo[t + 256] = (bf16_t)((v1-mu)*rstd*w[t + 256] + bvec[t + 256]);
  xo[t + 512] = (bf16_t)((v2-mu)*rstd*w[t + 512] + bvec[t + 512]);
}

// ---------------- QKV GEMM: 2-buf prefetch (measured-best, R4 bench) ----------------
__global__ __launch_bounds__(256) void gemm_qkv_kernel(
    const bf16_t* __restrict__ xn, const bf16_t* __restrict__ wt,
    const float* __restrict__ bq, const float* __restrict__ bk, const float* __restrict__ bv,
    bf16_t* __restrict__ qb, bf16_t* __restrict__ kb, bf16_t* __restrict__ vb)
{
  __shared__ __align__(16) bf16_t As[2][128][32];
  __shared__ __align__(16) bf16_t Bs[2][128][32];
  const int bm = blockIdx.x, by = blockIdx.y;
  const int mat = by/6, nb = by%6;
  const bf16_t* W = wt + (size_t)mat*EE*EE + (size_t)nb*128*EE;
  const float* bias = (mat==0)?bq:(mat==1)?bk:bv;
  bf16_t* outp = (mat==0)?qb:(mat==1)?kb:vb;
  const int t = threadIdx.x, lane = t&63, wid = t>>6;
  const int wr = wid>>1, wc = wid&1;
  const int lrow = lane&15, lk = lane>>4;
  const bf16_t* Ag = xn + (size_t)bm*128*EE;

  const int srow = t>>2, sp = t&3;
  const int sg = sp ^ ((srow>>1)&3);
  const int pcs = (lrow>>1)&3;

  auto stage = [&](int buf, int k0) {
    const bf16_t* asrc = Ag + (size_t)srow*EE + k0 + sg*8;
    const bf16_t* bsrc = W  + (size_t)srow*EE + k0 + sg*8;
    GLDS16(asrc,                 &As[buf][0][0] + t*8);
    GLDS16(asrc + (size_t)64*EE, &As[buf][0][0] + 2048 + t*8);
    GLDS16(bsrc,                 &Bs[buf][0][0] + t*8);
    GLDS16(bsrc + (size_t)64*EE, &Bs[buf][0][0] + 2048 + t*8);
  };

  f32x4 acc[4][4];
  #pragma unroll
  for (int i=0;i<4;++i)
    #pragma unroll
    for (int j=0;j<4;++j) acc[i][j] = (f32x4){0.f,0.f,0.f,0.f};

  stage(0, 0);
  __syncthreads();
  int cur = 0;
  for (int k0=0; k0<EE; k0+=32) {
    if (k0+32 < EE) stage(cur^1, k0+32);   // prefetch flies under compute
    bf16x8 af[4], bfv[4];
    #pragma unroll
    for (int mi=0;mi<4;++mi) af[mi]  = *(const bf16x8*)&As[cur][wr*64+mi*16+lrow][(lk^pcs)*8];
    #pragma unroll
    for (int ni=0;ni<4;++ni) bfv[ni] = *(const bf16x8*)&Bs[cur][wc*64+ni*16+lrow][(lk^pcs)*8];
    #pragma unroll
    for (int mi=0;mi<4;++mi)
      #pragma unroll
      for (int ni=0;ni<4;++ni)
        acc[mi][ni] = __builtin_amdgcn_mfma_f32_16x16x32_bf16(af[mi], bfv[ni], acc[mi][ni], 0,0,0);
    __syncthreads();   // drains prefetch + guards buffer reuse
    cur ^= 1;
  }
  const int m_base = bm*128 + wr*64;
  const int n_base = nb*128 + wc*64;
  #pragma unroll
  for (int ni=0;ni<4;++ni) {
    const int col = n_base + ni*16 + lrow;
    const float bias_v = bias[col];
    #pragma unroll
    for (int mi=0;mi<4;++mi) {
      #pragma unroll
      for (int r=0;r<4;++r) {
        int row = m_base + mi*16 + 4*lk + r;
        outp[(size_t)row*EE + col] = (bf16_t)(acc[mi][ni][r] + bias_v);
      }
    }
  }
}

// ---------------- V transpose: v[b,s,h,d] -> vt[(b*H+h)*D + d][s] ----------------
__global__ __launch_bounds__(256) void vtrans_kernel(
    const bf16_t* __restrict__ v, bf16_t* __restrict__ vt)
{
  __shared__ __align__(16) bf16_t tile[64][72];
  const int j0 = blockIdx.x*64, bh = blockIdx.y;
  const int b = bh/HH, h = bh%HH;
  const int t = threadIdx.x;
  #pragma unroll
  for (int it=0; it<2; ++it) {
    int idx = it*256+t, r = idx>>3, c8 = (idx&7)*8;
    *(bf16x8*)&tile[r][c8] = *(const bf16x8*)(v + (size_t)(b*SS + j0 + r)*EE + h*DD + c8);
  }
  __syncthreads();
  #pragma unroll
  for (int it=0; it<2; ++it) {
    int idx = it*256+t, d = idx>>3, c8 = (idx&7)*8;
    bf16x8 val;
    #pragma unroll
    for (int i=0;i<8;++i) val[i] = tile[c8+i][d];
    *(bf16x8*)(vt + ((size_t)bh*DD + d)*SS + j0 + c8) = val;
  }
}

// ---------------- flash attention (anti-causal: attend j >= i) ----------------
// NO LDS staging in the main loop (K/V tiles are L2/L1-resident; m169 lesson):
// K fragments via b128 global loads, V^T fragments via b64 global loads, all
// issued at iteration top; V latency hides under QK^T+softmax. No barriers ->
// waves fully independent. Fixed-max softmax (additive), snake remap kept.
// NOTE R7 bug fixed: K tile advance is += 64*EE (row-major, j is the row);
// V^T tile advance is += 64 (j is the column).
__global__ __launch_bounds__(256, 3) void attn_kernel(
    const bf16_t* __restrict__ qb, const bf16_t* __restrict__ kb,
    const bf16_t* __restrict__ vt, bf16_t* __restrict__ hb)
{
  // snake remap: blocks bid, bid+256, bid+512 share a CU -> complementary work
  const int bid = blockIdx.x;
  const int rnd = bid >> 8, g = bid & 255;
  const int item = (rnd == 1) ? (511 - g) : (rnd*256 + g);
  const int qt = item / 24, bh = item % 24;

  const int i0 = qt*64, b = bh/HH, h = bh%HH;
  const int t = threadIdx.x, lane = t&63, wid = t>>6;
  const int lrow = lane&15, lk = lane>>4;

  const bf16_t* kbase  = kb + (size_t)b*SS*EE + h*DD;   // K[j][d], row stride EE
  const bf16_t* vtbase = vt + (size_t)bh*DD*SS;          // V^T[d][j], row stride SS

  // Q fragment (B-operand): col=i=lrow, k=lk*8+e
  const bf16_t* qrow = qb + (size_t)(b*SS + i0 + wid*16 + lrow)*EE + h*DD;
  const bf16x8 qf0 = *(const bf16x8*)(qrow + lk*8);
  const bf16x8 qf1 = *(const bf16x8*)(qrow + 32 + lk*8);

  f32x4 acc_ot[4];
  #pragma unroll
  for (int i=0;i<4;++i) acc_ot[i] = (f32x4){0.f,0.f,0.f,0.f};
  float lsum = 0.f;
  const int iloc = wid*16 + lrow;

  // per-lane row pointers
  const bf16_t* kp = kbase + (size_t)(qt*64 + lrow)*EE + lk*8;      // + sj*16*EE
  const bf16_t* vp = vtbase + (size_t)lrow*SS + qt*64 + 4*lk;       // + sd*16*SS + sj*16

  // p = e^(qk/8 - 24) = 2^(a*0.1803369 - 34.62468); fixed max -> additive
#define ATTN_TILE(MASKED) do {                                               \
    bf16x8 kf[4][2];                                                         \
    _Pragma("unroll")                                                        \
    for (int sj=0;sj<4;++sj) {                                               \
      const bf16_t* kr = kp + (size_t)(sj*16)*EE;                            \
      kf[sj][0] = *(const bf16x8*)kr;                                        \
      kf[sj][1] = *(const bf16x8*)(kr + 32);                                 \
    }                                                                        \
    bf16x4 vf[4][4];                                                         \
    _Pragma("unroll")                                                        \
    for (int sd=0;sd<4;++sd) {                                               \
      const bf16_t* vr = vp + (size_t)(sd*16)*SS;                            \
      _Pragma("unroll")                                                      \
      for (int sj=0;sj<4;++sj) vf[sd][sj] = *(const bf16x4*)(vr + sj*16);    \
    }                                                                        \
    bf16x4 pb[4];                                                            \
    _Pragma("unroll")                                                        \
    for (int sj=0;sj<4;++sj) {                                               \
      f32x4 a = (f32x4){0.f,0.f,0.f,0.f};                                    \
      a = __builtin_amdgcn_mfma_f32_16x16x32_bf16(kf[sj][0], qf0, a, 0,0,0); \
      a = __builtin_amdgcn_mfma_f32_16x16x32_bf16(kf[sj][1], qf1, a, 0,0,0); \
      _Pragma("unroll")                                                      \
      for (int r=0;r<4;++r) {                                                \
        float ee = a[r]*0.180336878f - 34.6246784f;                          \
        if (MASKED && (sj*16 + 4*lk + r) < iloc) ee = -1e30f;                \
        float p = exp2f(ee);                                                 \
        lsum += p;                                                           \
        pb[sj][r] = (bf16_t)p;                                               \
      }                                                                      \
    }                                                                        \
    _Pragma("unroll")                                                        \
    for (int sd=0;sd<4;++sd)                                                 \
      _Pragma("unroll")                                                      \
      for (int sj=0;sj<4;++sj)                                               \
        acc_ot[sd] = mfma_16x16x16_bf16(vf[sd][sj], pb[sj], acc_ot[sd]);     \
  } while(0)

  // diagonal (masked) tile, peeled
  ATTN_TILE(true);
  kp += (size_t)64*EE; vp += 64;
#if !MFMA16_BUILTIN
  asm volatile("s_nop 7\n\ts_nop 7");
#endif

  for (int jt=qt+1; jt<SS/64; ++jt) {
    ATTN_TILE(false);
    kp += (size_t)64*EE; vp += 64;
#if !MFMA16_BUILTIN
    asm volatile("s_nop 7\n\ts_nop 7");
#endif
  }
#undef ATTN_TILE

  // deferred row-sum reduce (one shuffle pair for the whole kernel)
  lsum += __shfl_xor(lsum, 16);
  lsum += __shfl_xor(lsum, 32);
  const float inv = 1.0f / lsum;

  // epilogue: transpose O through padded LDS for coalesced stores
  __shared__ __align__(16) bf16_t Os[64][72];
  const int erow = wid*16 + lrow;
  #pragma unroll
  for (int sd=0;sd<4;++sd) {
    bf16x4 ov;
    #pragma unroll
    for (int r=0;r<4;++r) ov[r] = (bf16_t)(acc_ot[sd][r] * inv);
    *(bf16x4*)&Os[erow][sd*16 + 4*lk] = ov;
  }
  __syncthreads();
  const int rq = wid*16 + (lane>>2), c4 = lane&3;
  bf16x8 o0 = *(const bf16x8*)&Os[rq][c4*16];
  bf16x8 o1 = *(const bf16x8*)&Os[rq][c4*16 + 8];
  bf16_t* orow = hb + (size_t)(b*SS + i0 + rq)*EE + h*DD + c4*16;
  *(bf16x8*)orow = o0;
  *(bf16x8*)(orow+8) = o1;
}

// ---------------- output GEMM: out[4096,768] f32 = h @ Wo + bo ----------------
__global__ __launch_bounds__(256) void gemm_out_kernel(
    const bf16_t* __restrict__ hbuf, const bf16_t* __restrict__ wto,
    const float* __restrict__ bo, float* __restrict__ out)
{
  __shared__ __align__(16) bf16_t As[2][128][32];
  __shared__ __align__(16) bf16_t Bs[2][128][32];
  const int bm = blockIdx.x, nb = blockIdx.y;
  const bf16_t* W = wto + (size_t)nb*128*EE;
  const int t = threadIdx.x, lane = t&63, wid = t>>6;
  const int wr = wid>>1, wc = wid&1;
  const int lrow = lane&15, lk = lane>>4;
  const bf16_t* Ag = hbuf + (size_t)bm*128*EE;

  const int srow = t>>2, sp = t&3;
  const int sg = sp ^ ((srow>>1)&3);
  const int pcs = (lrow>>1)&3;

  auto stage = [&](int buf, int k0) {
    const bf16_t* asrc = Ag + (size_t)srow*EE + k0 + sg*8;
    const bf16_t* bsrc = W  + (size_t)srow*EE + k0 + sg*8;
    GLDS16(asrc,                 &As[buf][0][0] + t*8);
    GLDS16(asrc + (size_t)64*EE, &As[buf][0][0] + 2048 + t*8);
    GLDS16(bsrc,                 &Bs[buf][0][0] + t*8);
    GLDS16(bsrc + (size_t)64*EE, &Bs[buf][0][0] + 2048 + t*8);
  };

  f32x4 acc[4][4];
  #pragma unroll
  for (int i=0;i<4;++i)
    #pragma unroll
    for (int j=0;j<4;++j) acc[i][j] = (f32x4){0.f,0.f,0.f,0.f};

  stage(0, 0);
  __syncthreads();
  int cur = 0;
  for (int k0=0; k0<EE; k0+=32) {
    if (k0+32 < EE) stage(cur^1, k0+32);
    bf16x8 af[4], bfv[4];
    #pragma unroll
    for (int mi=0;mi<4;++mi) af[mi]  = *(const bf16x8*)&As[cur][wr*64+mi*16+lrow][(lk^pcs)*8];
    #pragma unroll
    for (int ni=0;ni<4;++ni) bfv[ni] = *(const bf16x8*)&Bs[cur][wc*64+ni*16+lrow][(lk^pcs)*8];
    #pragma unroll
    for (int mi=0;mi<4;++mi)
      #pragma unroll
      for (int ni=0;ni<4;++ni)
        acc[mi][ni] = __builtin_amdgcn_mfma_f32_16x16x32_bf16(af[mi], bfv[ni], acc[mi][ni], 0,0,0);
    __syncthreads();
    cur ^= 1;
  }
  const int m_base = bm*128 + wr*64;
  const int n_base = nb*128 + wc*64;
  #pragma unroll
  for (int ni=0;ni<4;++ni) {
    const int col = n_base + ni*16 + lrow;
    const float bias_v = bo[col];
    #pragma unroll
    for (int mi=0;mi<4;++mi) {
      #pragma unroll
      for (int r=0;r<4;++r) {
        int row = m_base + mi*16 + 4*lk + r;
        out[(size_t)row*EE + col] = acc[mi][ni][r] + bias_v;
      }
    }
  }
}

extern "C" void kernel_launch(void* const* d_in, const int* in_sizes, int n_in,
                              void* d_out, int out_size, void* d_ws, size_t ws_size,
                              hipStream_t stream) {
  const float* x    = (const float*)d_in[0];
  const float* ln_w = (const float*)d_in[1];
  const float* ln_b = (const float*)d_in[2];
  const float* wq   = (const float*)d_in[3];
  const float* bq   = (const float*)d_in[4];
  const float* wk   = (const float*)d_in[5];
  const float* bk   = (const float*)d_in[6];
  const float* wv   = (const float*)d_in[7];
  const float* bv   = (const float*)d_in[8];
  const float* wo   = (const float*)d_in[9];
  const float* bo   = (const float*)d_in[10];
  float* out = (float*)d_out;

  char* ws = (char*)d_ws;
  bf16_t* wt  = (bf16_t*)(ws);
  bf16_t* xn  = (bf16_t*)(ws + 4718592);
  bf16_t* qb  = (bf16_t*)(ws + 11010048);
  bf16_t* kb  = (bf16_t*)(ws + 17301504);
  bf16_t* vb  = (bf16_t*)(ws + 23592960);
  bf16_t* vtb = (bf16_t*)(ws + 29884416);
  bf16_t* hb  = (bf16_t*)(ws + 36175872);

  pack_w_kernel  <<<dim3(12,12,4), 256, 0, stream>>>(wq, wk, wv, wo, wt);
  ln_kernel      <<<dim3(NROW),    256, 0, stream>>>(x, ln_w, ln_b, xn);
  gemm_qkv_kernel<<<dim3(32,18),   256, 0, stream>>>(xn, wt, bq, bk, bv, qb, kb, vb);
  vtrans_kernel  <<<dim3(32,24),   256, 0, stream>>>(vb, vtb);
  attn_kernel    <<<dim3(768),     256, 0, stream>>>(qb, kb, vtb, hb);
  gemm_out_kernel<<<dim3(32,6),    256, 0, stream>>>(hb, wt + (size_t)3*EE*EE, bo, out);
}

// Round 9
// 98.170 us; speedup vs baseline: 2.0614x; 2.0614x over previous
//
#include <hip/hip_runtime.h>

typedef __bf16 bf16_t;
typedef __bf16 bf16x8 __attribute__((ext_vector_type(8)));
typedef __bf16 bf16x4 __attribute__((ext_vector_type(4)));
typedef short  s16x4  __attribute__((ext_vector_type(4)));
typedef float  f32x4  __attribute__((ext_vector_type(4)));
typedef unsigned int u32;

#define BB 2
#define SS 2048
#define EE 768
#define HH 12
#define DD 64
#define NROW (BB*SS)   // 4096

// async global->LDS, 16B per lane. LDS dest = firstlane(base)+lane*16 (linear).
#define GLDS16(gp, lp) __builtin_amdgcn_global_load_lds( \
    (const __attribute__((address_space(1))) u32*)(gp),   \
    (__attribute__((address_space(3))) u32*)(lp), 16, 0, 0)

#if __has_builtin(__builtin_amdgcn_mfma_f32_16x16x16bf16_1k)
#define MFMA16_BUILTIN 1
static __device__ __forceinline__ f32x4 mfma_16x16x16_bf16(bf16x4 a, bf16x4 b, f32x4 c) {
  return __builtin_amdgcn_mfma_f32_16x16x16bf16_1k(
      __builtin_bit_cast(s16x4, a), __builtin_bit_cast(s16x4, b), c, 0, 0, 0);
}
#else
#define MFMA16_BUILTIN 0
static __device__ __forceinline__ f32x4 mfma_16x16x16_bf16(bf16x4 a, bf16x4 b, f32x4 c) {
  asm volatile("v_mfma_f32_16x16x16_bf16 %0, %1, %2, %0" : "+v"(c) : "v"(a), "v"(b));
  return c;
}
#endif

// ---------------- pack weights: wt[z][n][k] = w_z[k][n] (bf16) ----------------
__global__ __launch_bounds__(256) void pack_w_kernel(
    const float* __restrict__ wq, const float* __restrict__ wk,
    const float* __restrict__ wv, const float* __restrict__ wo,
    bf16_t* __restrict__ wt)
{
  __shared__ float tile[64][65];
  const float* src = (blockIdx.z==0)?wq:(blockIdx.z==1)?wk:(blockIdx.z==2)?wv:wo;
  const int k0 = blockIdx.x*64, n0 = blockIdx.y*64;
  const int t = threadIdx.x;
  #pragma unroll
  for (int it=0; it<16; ++it) {
    int idx = it*256+t, r = idx>>6, c = idx&63;
    tile[r][c] = src[(size_t)(k0+r)*EE + n0 + c];
  }
  __syncthreads();
  bf16_t* dst = wt + (size_t)blockIdx.z*EE*EE;
  #pragma unroll
  for (int it=0; it<16; ++it) {
    int idx = it*256+t, r = idx>>6, c = idx&63;
    dst[(size_t)(n0+r)*EE + k0 + c] = (bf16_t)tile[c][r];
  }
}

// ---------------- LayerNorm (fp32 in, bf16 out) ----------------
__global__ __launch_bounds__(256) void ln_kernel(
    const float* __restrict__ x, const float* __restrict__ w,
    const float* __restrict__ bvec, bf16_t* __restrict__ xn)
{
  const int row = blockIdx.x, t = threadIdx.x;
  const float* xr = x + (size_t)row*EE;
  float v0 = xr[t], v1 = xr[t+256], v2 = xr[t+512];
  float s  = v0+v1+v2;
  float ss = v0*v0 + v1*v1 + v2*v2;
  #pragma unroll
  for (int m=1; m<64; m<<=1) { s += __shfl_xor(s,m); ss += __shfl_xor(ss,m); }
  __shared__ float red[2][4];
  const int wid = t>>6, lane = t&63;
  if (lane==0) { red[0][wid]=s; red[1][wid]=ss; }
  __syncthreads();
  s  = red[0][0]+red[0][1]+red[0][2]+red[0][3];
  ss = red[1][0]+red[1][1]+red[1][2]+red[1][3];
  const float mu   = s*(1.0f/EE);
  const float rstd = rsqrtf(ss*(1.0f/EE) - mu*mu + 1e-5f);
  bf16_t* xo = xn + (size_t)row*EE;
  xo[t      ] = (bf16_t)((v0-mu)*rstd*w[t      ] + bvec[t      ]);
  xo[t + 256] = (bf16_t)((v1-mu)*rstd*w[t + 256] + bvec[t + 256]);
  xo[t + 512] = (bf16_t)((v2-mu)*rstd*w[t + 512] + bvec[t + 512]);
}

// ---------------- QKV GEMM: 2-buf prefetch (measured-best, R4 bench) ----------------
__global__ __launch_bounds__(256) void gemm_qkv_kernel(
    const bf16_t* __restrict__ xn, const bf16_t* __restrict__ wt,
    const float* __restrict__ bq, const float* __restrict__ bk, const float* __restrict__ bv,
    bf16_t* __restrict__ qb, bf16_t* __restrict__ kb, bf16_t* __restrict__ vb)
{
  __shared__ __align__(16) bf16_t As[2][128][32];
  __shared__ __align__(16) bf16_t Bs[2][128][32];
  const int bm = blockIdx.x, by = blockIdx.y;
  const int mat = by/6, nb = by%6;
  const bf16_t* W = wt + (size_t)mat*EE*EE + (size_t)nb*128*EE;
  const float* bias = (mat==0)?bq:(mat==1)?bk:bv;
  bf16_t* outp = (mat==0)?qb:(mat==1)?kb:vb;
  const int t = threadIdx.x, lane = t&63, wid = t>>6;
  const int wr = wid>>1, wc = wid&1;
  const int lrow = lane&15, lk = lane>>4;
  const bf16_t* Ag = xn + (size_t)bm*128*EE;

  const int srow = t>>2, sp = t&3;
  const int sg = sp ^ ((srow>>1)&3);
  const int pcs = (lrow>>1)&3;

  auto stage = [&](int buf, int k0) {
    const bf16_t* asrc = Ag + (size_t)srow*EE + k0 + sg*8;
    const bf16_t* bsrc = W  + (size_t)srow*EE + k0 + sg*8;
    GLDS16(asrc,                 &As[buf][0][0] + t*8);
    GLDS16(asrc + (size_t)64*EE, &As[buf][0][0] + 2048 + t*8);
    GLDS16(bsrc,                 &Bs[buf][0][0] + t*8);
    GLDS16(bsrc + (size_t)64*EE, &Bs[buf][0][0] + 2048 + t*8);
  };

  f32x4 acc[4][4];
  #pragma unroll
  for (int i=0;i<4;++i)
    #pragma unroll
    for (int j=0;j<4;++j) acc[i][j] = (f32x4){0.f,0.f,0.f,0.f};

  stage(0, 0);
  __syncthreads();
  int cur = 0;
  for (int k0=0; k0<EE; k0+=32) {
    if (k0+32 < EE) stage(cur^1, k0+32);   // prefetch flies under compute
    bf16x8 af[4], bfv[4];
    #pragma unroll
    for (int mi=0;mi<4;++mi) af[mi]  = *(const bf16x8*)&As[cur][wr*64+mi*16+lrow][(lk^pcs)*8];
    #pragma unroll
    for (int ni=0;ni<4;++ni) bfv[ni] = *(const bf16x8*)&Bs[cur][wc*64+ni*16+lrow][(lk^pcs)*8];
    #pragma unroll
    for (int mi=0;mi<4;++mi)
      #pragma unroll
      for (int ni=0;ni<4;++ni)
        acc[mi][ni] = __builtin_amdgcn_mfma_f32_16x16x32_bf16(af[mi], bfv[ni], acc[mi][ni], 0,0,0);
    __syncthreads();   // drains prefetch + guards buffer reuse
    cur ^= 1;
  }
  const int m_base = bm*128 + wr*64;
  const int n_base = nb*128 + wc*64;
  #pragma unroll
  for (int ni=0;ni<4;++ni) {
    const int col = n_base + ni*16 + lrow;
    const float bias_v = bias[col];
    #pragma unroll
    for (int mi=0;mi<4;++mi) {
      #pragma unroll
      for (int r=0;r<4;++r) {
        int row = m_base + mi*16 + 4*lk + r;
        outp[(size_t)row*EE + col] = (bf16_t)(acc[mi][ni][r] + bias_v);
      }
    }
  }
}

// ---------------- V transpose: v[b,s,h,d] -> vt[(b*H+h)*D + d][s] ----------------
__global__ __launch_bounds__(256) void vtrans_kernel(
    const bf16_t* __restrict__ v, bf16_t* __restrict__ vt)
{
  __shared__ __align__(16) bf16_t tile[64][72];
  const int j0 = blockIdx.x*64, bh = blockIdx.y;
  const int b = bh/HH, h = bh%HH;
  const int t = threadIdx.x;
  #pragma unroll
  for (int it=0; it<2; ++it) {
    int idx = it*256+t, r = idx>>3, c8 = (idx&7)*8;
    *(bf16x8*)&tile[r][c8] = *(const bf16x8*)(v + (size_t)(b*SS + j0 + r)*EE + h*DD + c8);
  }
  __syncthreads();
  #pragma unroll
  for (int it=0; it<2; ++it) {
    int idx = it*256+t, d = idx>>3, c8 = (idx&7)*8;
    bf16x8 val;
    #pragma unroll
    for (int i=0;i<8;++i) val[i] = tile[c8+i][d];
    *(bf16x8*)(vt + ((size_t)bh*DD + d)*SS + j0 + c8) = val;
  }
}

// ---------------- flash attention (anti-causal: attend j >= i) ----------------
// Split-j uniform segments + XCD-PINNED mapping: 1512 blocks = 8 XCD x 189.
// xcd = bid&7 (dispatch round-robin), each XCD serves bh in {xcd, xcd+8, xcd+16}
// -> that XCD's L2 holds only 3 heads' K/V+Q (3MB < 4MB) across ALL segments.
// Fixes R5's L2 thrash (FETCH 65MB) while keeping uniform work (fixes R4's
// tail). Fixed-max softmax (p=e^(S-24), additive partials); staged 2-buf loop.
__global__ __launch_bounds__(256) void attn_kernel(
    const bf16_t* __restrict__ qb, const bf16_t* __restrict__ kb,
    const bf16_t* __restrict__ vt, bf16_t* __restrict__ hb,
    float* __restrict__ pO, float* __restrict__ pl)
{
  __shared__ __align__(16) bf16_t Ks[2][64][64];   // K tile [j][d]
  __shared__ __align__(16) bf16_t Vts[2][64][64];  // V^T tile [d][j]

  // XCD-pinned decode
  const int bid = blockIdx.x;            // 0..1511
  const int xcd = bid & 7, idx = bid >> 3;   // idx 0..188
  const int bh = xcd + 8*(idx % 3);
  const int s  = idx / 3;                // 0..62
  int qt, seg;
  if (s < 30)      { qt = s/3;           seg = s%3;       }
  else if (s < 52) { qt = 10 + (s-30)/2; seg = (s-30)&1;  }
  else             { qt = 21 + (s-52);   seg = 0;         }
  const int L = 32 - qt;
  const int nseg = (qt<10) ? 3 : (qt<21) ? 2 : 1;
  const int base = L/nseg, rem = L%nseg;
  const int jt0 = qt + seg*base + (seg<rem ? seg : rem);
  const int len = base + (seg<rem ? 1 : 0);

  const int i0 = qt*64, b = bh/HH, h = bh%HH;
  const int t = threadIdx.x, lane = t&63, wid = t>>6;
  const int lrow = lane&15, lk = lane>>4;

  const int srow = t>>3, sp = t&7;
  const int sgc = sp ^ (srow&7);
  const bf16_t* kbase  = kb + (size_t)b*SS*EE + h*DD;
  const bf16_t* vtbase = vt + (size_t)bh*DD*SS;

  const bf16_t* qrow = qb + (size_t)(b*SS + i0 + wid*16 + lrow)*EE + h*DD;
  const bf16x8 qf0 = *(const bf16x8*)(qrow + lk*8);
  const bf16x8 qf1 = *(const bf16x8*)(qrow + 32 + lk*8);

  f32x4 acc_ot[4];
  #pragma unroll
  for (int i=0;i<4;++i) acc_ot[i] = (f32x4){0.f,0.f,0.f,0.f};
  float lsum = 0.f;
  const int iloc = wid*16 + lrow;
  const int kkey = lrow&7;

  auto stage = [&](int buf, int jt) {
    const int j0v = jt*64;
    const bf16_t* ksrc = kbase  + (size_t)(j0v + srow)*EE + sgc*8;
    const bf16_t* vsrc = vtbase + (size_t)srow*SS + j0v + sgc*8;
    GLDS16(ksrc,                 &Ks[buf][0][0]  + t*8);
    GLDS16(ksrc + (size_t)32*EE, &Ks[buf][0][0]  + 2048 + t*8);
    GLDS16(vsrc,                 &Vts[buf][0][0] + t*8);
    GLDS16(vsrc + (size_t)32*SS, &Vts[buf][0][0] + 2048 + t*8);
  };

  // p = e^(qk/8 - 24) = 2^(a*0.1803369 - 34.62468)
#define ATTN_TILE(CUR, MASKED) do {                                          \
    float e[4][4];                                                           \
    _Pragma("unroll")                                                        \
    for (int sj=0;sj<4;++sj) {                                               \
      const bf16_t* krow = &Ks[CUR][sj*16+lrow][0];                          \
      bf16x8 kf0 = *(const bf16x8*)(krow + ((lk^kkey)<<3));                  \
      bf16x8 kf1 = *(const bf16x8*)(krow + (((lk+4)^kkey)<<3));              \
      f32x4 a = (f32x4){0.f,0.f,0.f,0.f};                                    \
      a = __builtin_amdgcn_mfma_f32_16x16x32_bf16(kf0, qf0, a, 0,0,0);       \
      a = __builtin_amdgcn_mfma_f32_16x16x32_bf16(kf1, qf1, a, 0,0,0);       \
      _Pragma("unroll")                                                      \
      for (int r=0;r<4;++r) {                                                \
        float ee = a[r]*0.180336878f - 34.6246784f;                          \
        if (MASKED && (sj*16 + 4*lk + r) < iloc) ee = -1e30f;                \
        e[sj][r] = ee;                                                       \
      }                                                                      \
    }                                                                        \
    bf16x4 pb[4];                                                            \
    _Pragma("unroll")                                                        \
    for (int sj=0;sj<4;++sj)                                                 \
      _Pragma("unroll")                                                      \
      for (int r=0;r<4;++r) {                                                \
        float p = exp2f(e[sj][r]);                                           \
        lsum += p;                                                           \
        pb[sj][r] = (bf16_t)p;                                               \
      }                                                                      \
    _Pragma("unroll")                                                        \
    for (int sd=0;sd<4;++sd) {                                               \
      const bf16_t* vrow = &Vts[CUR][sd*16+lrow][0];                         \
      _Pragma("unroll")                                                      \
      for (int sj=0;sj<4;++sj) {                                             \
        bf16x4 vf = *(const bf16x4*)(vrow + (((2*sj+(lk>>1))^kkey)<<3) + ((lk&1)<<2)); \
        acc_ot[sd] = mfma_16x16x16_bf16(vf, pb[sj], acc_ot[sd]);             \
      }                                                                      \
    }                                                                        \
  } while(0)

  stage(0, jt0);
  __syncthreads();                 // buf0 ready
  if (len > 1) stage(1, jt0+1);    // prefetch next before first compute
  if (seg == 0) { ATTN_TILE(0, true); } else { ATTN_TILE(0, false); }
#if !MFMA16_BUILTIN
  asm volatile("s_nop 7\n\ts_nop 7");
#endif
  __syncthreads();

  int cur = 1;
  for (int it2=1; it2<len; ++it2) {
    if (it2+1 < len) stage(cur^1, jt0+it2+1);
    ATTN_TILE(cur, false);
#if !MFMA16_BUILTIN
    asm volatile("s_nop 7\n\ts_nop 7");
#endif
    __syncthreads();
    cur ^= 1;
  }
#undef ATTN_TILE

  // per-row lsum (one shuffle pair for the whole kernel)
  lsum += __shfl_xor(lsum, 16);
  lsum += __shfl_xor(lsum, 32);

  if (nseg > 1) {
    // partial path: raw f32 O^T + lsum to scratch (additive across segments)
    const size_t slot = ((size_t)qt*24 + bh)*3 + seg;
    float* po = pO + slot*4096 + (size_t)(wid*16 + lrow)*64;
    #pragma unroll
    for (int sd=0;sd<4;++sd)
      *(f32x4*)(po + sd*16 + 4*lk) = acc_ot[sd];
    if (lane < 16) pl[slot*64 + wid*16 + lrow] = lsum;
    return;
  }

  // direct path: normalize, transpose O through Ks[0], coalesced store
  const float inv = 1.0f / lsum;
  const int erow = wid*16 + lrow, ekey = erow&7;
  #pragma unroll
  for (int sd=0;sd<4;++sd) {
    bf16x4 ov;
    #pragma unroll
    for (int r=0;r<4;++r) ov[r] = (bf16_t)(acc_ot[sd][r] * inv);
    *(bf16x4*)(&Ks[0][erow][0] + (((2*sd+(lk>>1))^ekey)<<3) + ((lk&1)<<2)) = ov;
  }
  __syncthreads();
  const int rq = wid*16 + (lane>>2), rkey = rq&7, c4 = lane&3;
  bf16x8 o0 = *(const bf16x8*)(&Ks[0][rq][0] + (((2*c4  )^rkey)<<3));
  bf16x8 o1 = *(const bf16x8*)(&Ks[0][rq][0] + (((2*c4+1)^rkey)<<3));
  bf16_t* orow = hb + (size_t)(b*SS + i0 + rq)*EE + h*DD + c4*16;
  *(bf16x8*)orow = o0;
  *(bf16x8*)(orow+8) = o1;
}

// ---------------- combine split-qt partials: hb = (sum O_seg) / (sum l_seg) ----------------
__global__ __launch_bounds__(256) void attn_combine_kernel(
    const float* __restrict__ pO, const float* __restrict__ pl,
    bf16_t* __restrict__ hb)
{
  const int qt = blockIdx.x;   // 0..20 (only split qts)
  const int bh = blockIdx.y;   // 0..23
  const int nseg = (qt < 10) ? 3 : 2;
  const int t = threadIdx.x;
  const int q = t >> 2, d0 = (t & 3) * 16;
  const size_t slot = ((size_t)qt*24 + bh)*3;

  float l = pl[slot*64 + q] + pl[(slot+1)*64 + q];
  if (nseg == 3) l += pl[(slot+2)*64 + q];
  const float inv = 1.0f / l;

  const float* o0 = pO + (slot  )*4096 + (size_t)q*64 + d0;
  const float* o1 = pO + (slot+1)*4096 + (size_t)q*64 + d0;
  const float* o2 = pO + (slot+2)*4096 + (size_t)q*64 + d0;
  const int b = bh/HH, h = bh%HH;
  bf16_t* orow = hb + (size_t)(b*SS + qt*64 + q)*EE + h*DD + d0;

  #pragma unroll
  for (int c=0;c<4;++c) {
    f32x4 v = *(const f32x4*)(o0 + c*4);
    f32x4 v1 = *(const f32x4*)(o1 + c*4);
    v += v1;
    if (nseg == 3) { f32x4 v2 = *(const f32x4*)(o2 + c*4); v += v2; }
    bf16x4 ov;
    #pragma unroll
    for (int i=0;i<4;++i) ov[i] = (bf16_t)(v[i]*inv);
    *(bf16x4*)(orow + c*4) = ov;
  }
}

// ---------------- output GEMM: out[4096,768] f32 = h @ Wo + bo ----------------
__global__ __launch_bounds__(256) void gemm_out_kernel(
    const bf16_t* __restrict__ hbuf, const bf16_t* __restrict__ wto,
    const float* __restrict__ bo, float* __restrict__ out)
{
  __shared__ __align__(16) bf16_t As[2][128][32];
  __shared__ __align__(16) bf16_t Bs[2][128][32];
  const int bm = blockIdx.x, nb = blockIdx.y;
  const bf16_t* W = wto + (size_t)nb*128*EE;
  const int t = threadIdx.x, lane = t&63, wid = t>>6;
  const int wr = wid>>1, wc = wid&1;
  const int lrow = lane&15, lk = lane>>4;
  const bf16_t* Ag = hbuf + (size_t)bm*128*EE;

  const int srow = t>>2, sp = t&3;
  const int sg = sp ^ ((srow>>1)&3);
  const int pcs = (lrow>>1)&3;

  auto stage = [&](int buf, int k0) {
    const bf16_t* asrc = Ag + (size_t)srow*EE + k0 + sg*8;
    const bf16_t* bsrc = W  + (size_t)srow*EE + k0 + sg*8;
    GLDS16(asrc,                 &As[buf][0][0] + t*8);
    GLDS16(asrc + (size_t)64*EE, &As[buf][0][0] + 2048 + t*8);
    GLDS16(bsrc,                 &Bs[buf][0][0] + t*8);
    GLDS16(bsrc + (size_t)64*EE, &Bs[buf][0][0] + 2048 + t*8);
  };

  f32x4 acc[4][4];
  #pragma unroll
  for (int i=0;i<4;++i)
    #pragma unroll
    for (int j=0;j<4;++j) acc[i][j] = (f32x4){0.f,0.f,0.f,0.f};

  stage(0, 0);
  __syncthreads();
  int cur = 0;
  for (int k0=0; k0<EE; k0+=32) {
    if (k0+32 < EE) stage(cur^1, k0+32);
    bf16x8 af[4], bfv[4];
    #pragma unroll
    for (int mi=0;mi<4;++mi) af[mi]  = *(const bf16x8*)&As[cur][wr*64+mi*16+lrow][(lk^pcs)*8];
    #pragma unroll
    for (int ni=0;ni<4;++ni) bfv[ni] = *(const bf16x8*)&Bs[cur][wc*64+ni*16+lrow][(lk^pcs)*8];
    #pragma unroll
    for (int mi=0;mi<4;++mi)
      #pragma unroll
      for (int ni=0;ni<4;++ni)
        acc[mi][ni] = __builtin_amdgcn_mfma_f32_16x16x32_bf16(af[mi], bfv[ni], acc[mi][ni], 0,0,0);
    __syncthreads();
    cur ^= 1;
  }
  const int m_base = bm*128 + wr*64;
  const int n_base = nb*128 + wc*64;
  #pragma unroll
  for (int ni=0;ni<4;++ni) {
    const int col = n_base + ni*16 + lrow;
    const float bias_v = bo[col];
    #pragma unroll
    for (int mi=0;mi<4;++mi) {
      #pragma unroll
      for (int r=0;r<4;++r) {
        int row = m_base + mi*16 + 4*lk + r;
        out[(size_t)row*EE + col] = acc[mi][ni][r] + bias_v;
      }
    }
  }
}

extern "C" void kernel_launch(void* const* d_in, const int* in_sizes, int n_in,
                              void* d_out, int out_size, void* d_ws, size_t ws_size,
                              hipStream_t stream) {
  const float* x    = (const float*)d_in[0];
  const float* ln_w = (const float*)d_in[1];
  const float* ln_b = (const float*)d_in[2];
  const float* wq   = (const float*)d_in[3];
  const float* bq   = (const float*)d_in[4];
  const float* wk   = (const float*)d_in[5];
  const float* bk   = (const float*)d_in[6];
  const float* wv   = (const float*)d_in[7];
  const float* bv   = (const float*)d_in[8];
  const float* wo   = (const float*)d_in[9];
  const float* bo   = (const float*)d_in[10];
  float* out = (float*)d_out;

  char* ws = (char*)d_ws;
  bf16_t* wt  = (bf16_t*)(ws);
  bf16_t* xn  = (bf16_t*)(ws + 4718592);
  bf16_t* qb  = (bf16_t*)(ws + 11010048);
  bf16_t* kb  = (bf16_t*)(ws + 17301504);
  bf16_t* vb  = (bf16_t*)(ws + 23592960);
  bf16_t* vtb = (bf16_t*)(ws + 29884416);
  bf16_t* hb  = (bf16_t*)(ws + 36175872);
  float*  pO  = (float*)(ws + 42467328);   // [32][24][3][64*64] f32 = 37.75MB
  float*  pl  = (float*)(ws + 80216064);   // [32][24][3][64]    f32 = 0.59MB

  pack_w_kernel  <<<dim3(12,12,4), 256, 0, stream>>>(wq, wk, wv, wo, wt);
  ln_kernel      <<<dim3(NROW),    256, 0, stream>>>(x, ln_w, ln_b, xn);
  gemm_qkv_kernel<<<dim3(32,18),   256, 0, stream>>>(xn, wt, bq, bk, bv, qb, kb, vb);
  vtrans_kernel  <<<dim3(32,24),   256, 0, stream>>>(vb, vtb);
  attn_kernel    <<<dim3(1512),    256, 0, stream>>>(qb, kb, vtb, hb, pO, pl);
  attn_combine_kernel<<<dim3(21,24), 256, 0, stream>>>(pO, pl, hb);
  gemm_out_kernel<<<dim3(32,6),    256, 0, stream>>>(hb, wt + (size_t)3*EE*EE, bo, out);
}